// Round 7
// baseline (166.739 us; speedup 1.0000x reference)
//
#include <hip/hip_runtime.h>

#define BATCH 4096
#define IN_DIM 256
#define GRID_N 64
#define HID 128
constexpr float BN_EPS = 1e-5f;

// ---------------- workspace layout (bytes) ----------------
static const size_t O_MMP  = 0;                              // 128 blocks * 512 f partial min/max = 262144
static const size_t O_ZMIN = 262144;                         // 256 f
static const size_t O_INV  = 263168;                         // 256 f
static const size_t O_ST1  = 264192;                         // 512 f  (sum+sumsq, N=256)
static const size_t O_ST2  = 266240;                         // 256 f  (N=128)
static const size_t O_ST3  = 267264;                         // 128 f  (N=64)   [st1..st3 contiguous 896 f]
static const size_t O_ST   = 270336;                         // interleaved table 256*65*128 float2 = 17039360
static const size_t O_H    = O_ST + (size_t)256*65*128*8;    // 17309696
static const size_t O_A1   = O_H  + (size_t)4096*128*4;      // + 2 MB
static const size_t O_A2   = O_A1 + (size_t)4096*256*4;      // + 4 MB
static const size_t O_A3   = O_A2 + (size_t)4096*128*4;      // + 2 MB  (end ~ 26.7 MB)

// per-feature min/max partials (no atomics, no init) + zero the GEMM stats region
__global__ __launch_bounds__(256) void k_minmax(const float* __restrict__ x, float* __restrict__ mmp,
                                                float* __restrict__ stz){
    int f  = threadIdx.x;           // feature 0..255
    int r0 = blockIdx.x * 32;       // 128 blocks * 32 rows
    float mn = 1e30f, mx = -1e30f;
    #pragma unroll 4
    for (int r = 0; r < 32; ++r){
        float v = x[(size_t)(r0 + r)*IN_DIM + f];
        mn = fminf(mn, v); mx = fmaxf(mx, v);
    }
    mmp[(size_t)blockIdx.x*512 + f]       = mn;
    mmp[(size_t)blockIdx.x*512 + 256 + f] = mx;
    if (blockIdx.x == 0){
        for (int s = f; s < 896; s += 256) stz[s] = 0.f;   // st1|st2|st3 contiguous
    }
}

// interleaved prefix tables ST[i][K][h] = (S1, S2):
//   S1 = sum_{k<K} fs_sum[i,k,h], S2 = sum_{k<K} g_k*fs_sum[i,k,h]
// block 0 also reduces min/max partials -> zmin, inv.
__global__ __launch_bounds__(128) void k_tables(const float* __restrict__ fs, const float* __restrict__ grids,
                                                const float* __restrict__ mmp,
                                                float* __restrict__ zmin, float* __restrict__ inv,
                                                float2* __restrict__ ST){
    int i = blockIdx.x;     // 0..255
    int h = threadIdx.x;    // 0..127
    if (i == 0){
        for (int f = h; f < 256; f += 128){
            float mn = 1e30f, mx = -1e30f;
            #pragma unroll 8
            for (int p = 0; p < 128; ++p){
                mn = fminf(mn, mmp[(size_t)p*512 + f]);
                mx = fmaxf(mx, mmp[(size_t)p*512 + 256 + f]);
            }
            zmin[f] = mn;
            inv[f]  = 1.0f / (mx - mn + 1e-6f);
        }
    }
    const float* f0 = fs + ((size_t)(0*IN_DIM + i)*GRID_N)*HID + h;
    const float* f1 = fs + ((size_t)(1*IN_DIM + i)*GRID_N)*HID + h;
    const float* f2 = fs + ((size_t)(2*IN_DIM + i)*GRID_N)*HID + h;
    float2* st = ST + (size_t)i*65*HID + h;
    float acc1 = 0.f, acc2 = 0.f;
    st[0] = make_float2(0.f, 0.f);
    #pragma unroll 4
    for (int k = 0; k < 64; ++k){
        float fv = f0[(size_t)k*HID] + f1[(size_t)k*HID] + f2[(size_t)k*HID];
        float g  = grids[k];            // row 0 (identical across depth)
        acc1 += fv;
        acc2  = fmaf(g, fv, acc2);
        st[(size_t)(k+1)*HID] = make_float2(acc1, acc2);
    }
}

// h[b,:] = sum_i ( z*S1[i,K0,:] - S2[i,K0,:] )
// 1 row per block, 2 waves split the i-range, LDS combine; lane l covers h={2l,2l+1} via float4
__global__ __launch_bounds__(128) void k_gather(const float* __restrict__ x, const float* __restrict__ zmin,
                                                const float* __restrict__ inv, const float2* __restrict__ ST,
                                                float* __restrict__ h){
    __shared__ float2 pre[256];         // (z, byte-offset bitcast) per i
    __shared__ float2 part[64];         // wave1 partials
    const int tid = threadIdx.x;
    const int b   = blockIdx.x;

    // precompute z and table-row byte offsets (coalesced x reads, 2 per thread)
    for (int i = tid; i < 256; i += 128){
        float z = (x[(size_t)b*IN_DIM + i] - zmin[i]) * inv[i];
        int K0 = (int)(z * 63.0f) + 1;
        K0 = max(1, min(63, K0));
        unsigned off = ((unsigned)(i*65 + K0)) << 10;   // row stride = 128 float2 = 1024 B
        pre[i] = make_float2(z, __uint_as_float(off));
    }
    __syncthreads();

    const int w = tid >> 6;             // wave id: i-range [w*128, w*128+128)
    const int l = tid & 63;             // lane
    const char* base = (const char*)ST + (size_t)l * 16;
    float acc0 = 0.f, acc1 = 0.f;
    #pragma unroll 8
    for (int ii = 0; ii < 128; ++ii){
        float2 p = pre[w*128 + ii];     // wave-uniform LDS read -> broadcast
        float4 s = *reinterpret_cast<const float4*>(base + __float_as_uint(p.y));
        acc0 += fmaf(p.x, s.x, -s.y);   // h = 2l
        acc1 += fmaf(p.x, s.z, -s.w);   // h = 2l+1
    }
    if (w == 1) part[l] = make_float2(acc0, acc1);
    __syncthreads();
    if (w == 0){
        float2 q = part[l];
        *reinterpret_cast<float2*>(&h[(size_t)b*HID + 2*l]) =
            make_float2(acc0 + q.x, acc1 + q.y);
    }
}

// generic fp32 GEMM: C = relu(bn?(A) @ W + bias), + per-col sum/sumsq atomics
// tile 64x64, KC=32, 256 threads, thread = 4x4 micro-tile
template<int BN_IN>
__global__ __launch_bounds__(256) void k_gemm(const float* __restrict__ A, const float* __restrict__ W,
                                              const float* __restrict__ bias,
                                              const float* __restrict__ instats,
                                              const float* __restrict__ gam, const float* __restrict__ bet,
                                              float* __restrict__ C, float* __restrict__ ostats,
                                              int K, int N){
    __shared__ float As[64][33];
    __shared__ float Ws[32][64];
    __shared__ float bnsc[256], bnsh[256];
    __shared__ float red[16][16][8];

    const int tid = threadIdx.x;
    const int n0  = blockIdx.x * 64;
    const int b0  = blockIdx.y * 64;

    if (BN_IN){
        for (int k = tid; k < K; k += 256){
            float m  = instats[k]     * (1.0f/BATCH);
            float v  = instats[K + k] * (1.0f/BATCH) - m*m;
            float rs = rsqrtf(v + BN_EPS);
            float s  = gam[k]*rs;
            bnsc[k] = s;
            bnsh[k] = fmaf(-m, s, bet[k]);
        }
        __syncthreads();
    }

    const int nt = tid & 15;
    const int bt = tid >> 4;
    float acc[4][4];
    #pragma unroll
    for (int r = 0; r < 4; ++r)
        #pragma unroll
        for (int j = 0; j < 4; ++j) acc[r][j] = 0.f;

    for (int kc = 0; kc < K; kc += 32){
        #pragma unroll
        for (int idx = tid; idx < 64*32; idx += 256){
            int r = idx >> 5, k = idx & 31;
            float a = A[(size_t)(b0 + r)*K + kc + k];
            if (BN_IN) a = fmaf(a, bnsc[kc + k], bnsh[kc + k]);
            As[r][k] = a;
        }
        #pragma unroll
        for (int idx = tid; idx < 32*64; idx += 256){
            int k = idx >> 6, n = idx & 63;
            Ws[k][n] = W[(size_t)(kc + k)*N + n0 + n];
        }
        __syncthreads();
        #pragma unroll
        for (int k = 0; k < 32; ++k){
            float4 w = *reinterpret_cast<const float4*>(&Ws[k][nt*4]);
            float a0 = As[bt*4+0][k], a1 = As[bt*4+1][k], a2 = As[bt*4+2][k], a3 = As[bt*4+3][k];
            acc[0][0] = fmaf(a0, w.x, acc[0][0]); acc[0][1] = fmaf(a0, w.y, acc[0][1]);
            acc[0][2] = fmaf(a0, w.z, acc[0][2]); acc[0][3] = fmaf(a0, w.w, acc[0][3]);
            acc[1][0] = fmaf(a1, w.x, acc[1][0]); acc[1][1] = fmaf(a1, w.y, acc[1][1]);
            acc[1][2] = fmaf(a1, w.z, acc[1][2]); acc[1][3] = fmaf(a1, w.w, acc[1][3]);
            acc[2][0] = fmaf(a2, w.x, acc[2][0]); acc[2][1] = fmaf(a2, w.y, acc[2][1]);
            acc[2][2] = fmaf(a2, w.z, acc[2][2]); acc[2][3] = fmaf(a2, w.w, acc[2][3]);
            acc[3][0] = fmaf(a3, w.x, acc[3][0]); acc[3][1] = fmaf(a3, w.y, acc[3][1]);
            acc[3][2] = fmaf(a3, w.z, acc[3][2]); acc[3][3] = fmaf(a3, w.w, acc[3][3]);
        }
        __syncthreads();
    }

    float bs[4];
    #pragma unroll
    for (int j = 0; j < 4; ++j) bs[j] = bias[n0 + nt*4 + j];
    float lsum[4] = {0,0,0,0}, lsq[4] = {0,0,0,0};
    #pragma unroll
    for (int r = 0; r < 4; ++r){
        int brow = b0 + bt*4 + r;
        float vv[4];
        #pragma unroll
        for (int j = 0; j < 4; ++j){
            float v1 = acc[r][j] + bs[j];
            v1 = fmaxf(v1, 0.f);
            vv[j] = v1;
            lsum[j] += v1;
            lsq[j]  = fmaf(v1, v1, lsq[j]);
        }
        *reinterpret_cast<float4*>(&C[(size_t)brow*N + n0 + nt*4]) =
            make_float4(vv[0], vv[1], vv[2], vv[3]);
    }
    #pragma unroll
    for (int j = 0; j < 4; ++j){ red[bt][nt][j] = lsum[j]; red[bt][nt][4+j] = lsq[j]; }
    __syncthreads();
    for (int s = 8; s > 0; s >>= 1){
        if (bt < s){
            #pragma unroll
            for (int f = 0; f < 8; ++f) red[bt][nt][f] += red[bt+s][nt][f];
        }
        __syncthreads();
    }
    if (bt == 0){
        #pragma unroll
        for (int j = 0; j < 4; ++j){
            atomicAdd(&ostats[n0 + nt*4 + j],     red[0][nt][j]);
            atomicAdd(&ostats[N + n0 + nt*4 + j], red[0][nt][4+j]);
        }
    }
}

// out = BN(A3) @ w4 + b4
__global__ __launch_bounds__(256) void k_final(const float* __restrict__ A3, const float* __restrict__ st3,
                                               const float* __restrict__ g3, const float* __restrict__ be3,
                                               const float* __restrict__ w4, const float* __restrict__ b4,
                                               float* __restrict__ out){
    __shared__ float sc[64], sh[64];
    int t = threadIdx.x;
    if (t < 64){
        float m  = st3[t]      * (1.0f/BATCH);
        float v  = st3[64 + t] * (1.0f/BATCH) - m*m;
        float rs = rsqrtf(v + BN_EPS);
        float s  = g3[t]*rs;
        sc[t] = s * w4[t];
        sh[t] = fmaf(-m, s, be3[t]) * w4[t];
    }
    __syncthreads();
    int row = blockIdx.x*256 + t;
    const float* a = A3 + (size_t)row*64;
    float acc = b4[0];
    #pragma unroll
    for (int k = 0; k < 64; ++k){
        acc = fmaf(a[k], sc[k], acc);
        acc += sh[k];
    }
    out[row] = acc;
}

extern "C" void kernel_launch(void* const* d_in, const int* in_sizes, int n_in,
                              void* d_out, int out_size, void* d_ws, size_t ws_size,
                              hipStream_t stream){
    const float* x     = (const float*)d_in[0];
    const float* fs    = (const float*)d_in[1];
    const float* grids = (const float*)d_in[2];
    const float* w1 = (const float*)d_in[3];  const float* b1 = (const float*)d_in[4];
    const float* g1 = (const float*)d_in[5];  const float* be1= (const float*)d_in[6];
    const float* w2 = (const float*)d_in[7];  const float* b2 = (const float*)d_in[8];
    const float* g2 = (const float*)d_in[9];  const float* be2= (const float*)d_in[10];
    const float* w3 = (const float*)d_in[11]; const float* b3 = (const float*)d_in[12];
    const float* g3 = (const float*)d_in[13]; const float* be3= (const float*)d_in[14];
    const float* w4 = (const float*)d_in[15]; const float* b4 = (const float*)d_in[16];
    float* out = (float*)d_out;

    char* ws = (char*)d_ws;
    float* mmp    = (float*)(ws + O_MMP);
    float* zmin   = (float*)(ws + O_ZMIN);
    float* inv    = (float*)(ws + O_INV);
    float* st1    = (float*)(ws + O_ST1);
    float* st2    = (float*)(ws + O_ST2);
    float* st3    = (float*)(ws + O_ST3);
    float2* ST    = (float2*)(ws + O_ST);
    float* h      = (float*)(ws + O_H);
    float* A1     = (float*)(ws + O_A1);
    float* A2     = (float*)(ws + O_A2);
    float* A3     = (float*)(ws + O_A3);

    k_minmax<<<128, 256, 0, stream>>>(x, mmp, st1);
    k_tables<<<256, 128, 0, stream>>>(fs, grids, mmp, zmin, inv, ST);
    k_gather<<<4096, 128, 0, stream>>>(x, zmin, inv, ST, h);
    k_gemm<0><<<dim3(4, 64), 256, 0, stream>>>(h,  w1, b1, nullptr, nullptr, nullptr, A1, st1, 128, 256);
    k_gemm<1><<<dim3(2, 64), 256, 0, stream>>>(A1, w2, b2, st1, g1, be1,            A2, st2, 256, 128);
    k_gemm<1><<<dim3(1, 64), 256, 0, stream>>>(A2, w3, b3, st2, g2, be2,            A3, st3, 128, 64);
    k_final<<<16, 256, 0, stream>>>(A3, st3, g3, be3, w4, b4, out);
}

// Round 9
// 143.266 us; speedup vs baseline: 1.1638x; 1.1638x over previous
//
#include <hip/hip_runtime.h>
#include <hip/hip_fp16.h>

#define BATCH 4096
#define IN_DIM 256
#define GRID_N 64
#define HID 128
constexpr float BN_EPS = 1e-5f;

// ---------------- workspace layout (bytes) ----------------
static const size_t O_MM   = 0;        // 512 uint (min[256]@0xFF-init, max[256]@0x00-init)
static const size_t O_ST1  = 4096;     // stats L1 (512 f)
static const size_t O_ST2  = 6144;     // stats L2 (256 f)
static const size_t O_ST3  = 7168;     // stats L3 (128 f)
static const size_t O_STB  = 8192;     // packed fp16 table: 256*65*128 u32 = 8519680 B
static const size_t O_H    = O_STB + (size_t)256*65*128*4;  //  8527872
static const size_t O_A1   = O_H  + (size_t)4096*128*4;     // 10625024
static const size_t O_A2   = O_A1 + (size_t)4096*256*4;     // 14819328
static const size_t O_A3   = O_A2 + (size_t)4096*128*4;     // 16916480

__device__ __forceinline__ unsigned fmap(float f){
    unsigned u = __float_as_uint(f);
    return (u & 0x80000000u) ? ~u : (u ^ 0x80000000u);
}
__device__ __forceinline__ float funmap(unsigned k){
    return __uint_as_float((k & 0x80000000u) ? (k ^ 0x80000000u) : ~k);
}

// merged: blocks 0..127 = per-feature min/max (ordered-uint atomics);
//         blocks 128..383 = packed prefix tables STb[i][K][h] = pack(fp16(S1), fp16(-S2))
__global__ __launch_bounds__(256) void k_prep(const float* __restrict__ x, const float* __restrict__ fs,
                                              const float* __restrict__ grids,
                                              unsigned* __restrict__ mm, unsigned* __restrict__ STb){
    const int tid = threadIdx.x;
    if (blockIdx.x < 128){
        int f  = tid;                   // feature 0..255
        int r0 = blockIdx.x * 32;       // 32 rows per block
        unsigned mn = 0xFFFFFFFFu, mx = 0u;
        #pragma unroll 4
        for (int r = 0; r < 32; ++r){
            unsigned k = fmap(x[(size_t)(r0 + r)*IN_DIM + f]);
            mn = min(mn, k); mx = max(mx, k);
        }
        atomicMin(&mm[f], mn);
        atomicMax(&mm[256 + f], mx);
        return;
    }
    if (tid >= 128) return;
    const int i = blockIdx.x - 128;     // 0..255
    const int h = tid;                  // 0..127
    const float* f0 = fs + ((size_t)(0*IN_DIM + i)*GRID_N)*HID + h;
    const float* f1 = fs + ((size_t)(1*IN_DIM + i)*GRID_N)*HID + h;
    const float* f2 = fs + ((size_t)(2*IN_DIM + i)*GRID_N)*HID + h;
    unsigned* st = STb + (size_t)i*65*HID + h;
    float acc1 = 0.f, acc2 = 0.f;
    st[0] = 0u;
    #pragma unroll 4
    for (int k = 0; k < 64; ++k){
        float fv = f0[(size_t)k*HID] + f1[(size_t)k*HID] + f2[(size_t)k*HID];
        float g  = grids[k];            // row 0 (identical across depth)
        acc1 += fv;
        acc2  = fmaf(g, fv, acc2);
        __half2 hh = __halves2half2(__float2half_rn(acc1), __float2half_rn(-acc2));
        st[(size_t)(k+1)*HID] = *reinterpret_cast<unsigned*>(&hh);
    }
}

// h[b,:] = sum_i ( z*S1[i,K0,:] - S2[i,K0,:] )  [fp16 packed table]
// 2 waves/block, one batch row per wave; lane l covers h = {2l, 2l+1} via uint2 (8B)
__global__ __launch_bounds__(128) void k_gather(const float* __restrict__ x, const unsigned* __restrict__ mm,
                                                const unsigned* __restrict__ STb, float* __restrict__ h){
    __shared__ float2 pre[2][256];      // (z, byte-offset bitcast) per (row_local, i)
    const int tid = threadIdx.x;
    const int b0  = blockIdx.x * 2;

    // precompute z and table-row byte offsets; zmin/inv derived inline from mm (L2-hot)
    for (int idx = tid; idx < 2*256; idx += 128){
        int bl = idx >> 8, i = idx & 255;
        float mn  = funmap(mm[i]);
        float mx  = funmap(mm[256 + i]);
        float z   = (x[(size_t)(b0 + bl)*IN_DIM + i] - mn) * (1.0f / (mx - mn + 1e-6f));
        int K0 = (int)(z * 63.0f) + 1;
        K0 = max(1, min(63, K0));
        unsigned off = ((unsigned)(i*65 + K0)) << 9;    // row stride = 128 u32 = 512 B
        pre[bl][i] = make_float2(z, __uint_as_float(off));
    }
    __syncthreads();

    const int w = tid >> 6;             // wave id = local row
    const int l = tid & 63;             // lane
    const char* base = (const char*)STb + (size_t)l * 8;
    float acc0 = 0.f, acc1 = 0.f;
    #pragma unroll 8
    for (int i = 0; i < 256; ++i){
        float2 p = pre[w][i];           // wave-uniform LDS read -> broadcast
        uint2 u = *reinterpret_cast<const uint2*>(base + __float_as_uint(p.y));
        // lo16 = fp16(S1), hi16 = fp16(-S2)
        float2 f0 = __half22float2(*reinterpret_cast<__half2*>(&u.x));
        float2 f1 = __half22float2(*reinterpret_cast<__half2*>(&u.y));
        acc0 += fmaf(p.x, f0.x, f0.y);  // h = 2l
        acc1 += fmaf(p.x, f1.x, f1.y);  // h = 2l+1
    }
    *reinterpret_cast<float2*>(&h[(size_t)(b0 + w)*HID + 2*l]) = make_float2(acc0, acc1);
}

// generic fp32 GEMM: C = relu(bn?(A) @ W + bias), + per-col sum/sumsq atomics
// tile 64x64, KC=32, 256 threads, thread = 4x4 micro-tile
template<int BN_IN>
__global__ __launch_bounds__(256) void k_gemm(const float* __restrict__ A, const float* __restrict__ W,
                                              const float* __restrict__ bias,
                                              const float* __restrict__ instats,
                                              const float* __restrict__ gam, const float* __restrict__ bet,
                                              float* __restrict__ C, float* __restrict__ ostats,
                                              int K, int N){
    __shared__ float As[64][33];
    __shared__ float Ws[32][64];
    __shared__ float bnsc[256], bnsh[256];
    __shared__ float red[16][16][8];

    const int tid = threadIdx.x;
    const int n0  = blockIdx.x * 64;
    const int b0  = blockIdx.y * 64;

    if (BN_IN){
        for (int k = tid; k < K; k += 256){
            float m  = instats[k]     * (1.0f/BATCH);
            float v  = instats[K + k] * (1.0f/BATCH) - m*m;
            float rs = rsqrtf(v + BN_EPS);
            float s  = gam[k]*rs;
            bnsc[k] = s;
            bnsh[k] = fmaf(-m, s, bet[k]);
        }
        __syncthreads();
    }

    const int nt = tid & 15;
    const int bt = tid >> 4;
    float acc[4][4];
    #pragma unroll
    for (int r = 0; r < 4; ++r)
        #pragma unroll
        for (int j = 0; j < 4; ++j) acc[r][j] = 0.f;

    for (int kc = 0; kc < K; kc += 32){
        #pragma unroll
        for (int idx = tid; idx < 64*32; idx += 256){
            int r = idx >> 5, k = idx & 31;
            float a = A[(size_t)(b0 + r)*K + kc + k];
            if (BN_IN) a = fmaf(a, bnsc[kc + k], bnsh[kc + k]);
            As[r][k] = a;
        }
        #pragma unroll
        for (int idx = tid; idx < 32*64; idx += 256){
            int k = idx >> 6, n = idx & 63;
            Ws[k][n] = W[(size_t)(kc + k)*N + n0 + n];
        }
        __syncthreads();
        #pragma unroll
        for (int k = 0; k < 32; ++k){
            float4 w = *reinterpret_cast<const float4*>(&Ws[k][nt*4]);
            float a0 = As[bt*4+0][k], a1 = As[bt*4+1][k], a2 = As[bt*4+2][k], a3 = As[bt*4+3][k];
            acc[0][0] = fmaf(a0, w.x, acc[0][0]); acc[0][1] = fmaf(a0, w.y, acc[0][1]);
            acc[0][2] = fmaf(a0, w.z, acc[0][2]); acc[0][3] = fmaf(a0, w.w, acc[0][3]);
            acc[1][0] = fmaf(a1, w.x, acc[1][0]); acc[1][1] = fmaf(a1, w.y, acc[1][1]);
            acc[1][2] = fmaf(a1, w.z, acc[1][2]); acc[1][3] = fmaf(a1, w.w, acc[1][3]);
            acc[2][0] = fmaf(a2, w.x, acc[2][0]); acc[2][1] = fmaf(a2, w.y, acc[2][1]);
            acc[2][2] = fmaf(a2, w.z, acc[2][2]); acc[2][3] = fmaf(a2, w.w, acc[2][3]);
            acc[3][0] = fmaf(a3, w.x, acc[3][0]); acc[3][1] = fmaf(a3, w.y, acc[3][1]);
            acc[3][2] = fmaf(a3, w.z, acc[3][2]); acc[3][3] = fmaf(a3, w.w, acc[3][3]);
        }
        __syncthreads();
    }

    float bs[4];
    #pragma unroll
    for (int j = 0; j < 4; ++j) bs[j] = bias[n0 + nt*4 + j];
    float lsum[4] = {0,0,0,0}, lsq[4] = {0,0,0,0};
    #pragma unroll
    for (int r = 0; r < 4; ++r){
        int brow = b0 + bt*4 + r;
        float vv[4];
        #pragma unroll
        for (int j = 0; j < 4; ++j){
            float v1 = acc[r][j] + bs[j];
            v1 = fmaxf(v1, 0.f);
            vv[j] = v1;
            lsum[j] += v1;
            lsq[j]  = fmaf(v1, v1, lsq[j]);
        }
        *reinterpret_cast<float4*>(&C[(size_t)brow*N + n0 + nt*4]) =
            make_float4(vv[0], vv[1], vv[2], vv[3]);
    }
    #pragma unroll
    for (int j = 0; j < 4; ++j){ red[bt][nt][j] = lsum[j]; red[bt][nt][4+j] = lsq[j]; }
    __syncthreads();
    for (int s = 8; s > 0; s >>= 1){
        if (bt < s){
            #pragma unroll
            for (int f = 0; f < 8; ++f) red[bt][nt][f] += red[bt+s][nt][f];
        }
        __syncthreads();
    }
    if (bt == 0){
        #pragma unroll
        for (int j = 0; j < 4; ++j){
            atomicAdd(&ostats[n0 + nt*4 + j],     red[0][nt][j]);
            atomicAdd(&ostats[N + n0 + nt*4 + j], red[0][nt][4+j]);
        }
    }
}

// out = BN(A3) @ w4 + b4
__global__ __launch_bounds__(256) void k_final(const float* __restrict__ A3, const float* __restrict__ st3,
                                               const float* __restrict__ g3, const float* __restrict__ be3,
                                               const float* __restrict__ w4, const float* __restrict__ b4,
                                               float* __restrict__ out){
    __shared__ float sc[64], sh[64];
    int t = threadIdx.x;
    if (t < 64){
        float m  = st3[t]      * (1.0f/BATCH);
        float v  = st3[64 + t] * (1.0f/BATCH) - m*m;
        float rs = rsqrtf(v + BN_EPS);
        float s  = g3[t]*rs;
        sc[t] = s * w4[t];
        sh[t] = fmaf(-m, s, be3[t]) * w4[t];
    }
    __syncthreads();
    int row = blockIdx.x*256 + t;
    const float* a = A3 + (size_t)row*64;
    float acc = b4[0];
    #pragma unroll
    for (int k = 0; k < 64; ++k){
        acc = fmaf(a[k], sc[k], acc);
        acc += sh[k];
    }
    out[row] = acc;
}

extern "C" void kernel_launch(void* const* d_in, const int* in_sizes, int n_in,
                              void* d_out, int out_size, void* d_ws, size_t ws_size,
                              hipStream_t stream){
    const float* x     = (const float*)d_in[0];
    const float* fs    = (const float*)d_in[1];
    const float* grids = (const float*)d_in[2];
    const float* w1 = (const float*)d_in[3];  const float* b1 = (const float*)d_in[4];
    const float* g1 = (const float*)d_in[5];  const float* be1= (const float*)d_in[6];
    const float* w2 = (const float*)d_in[7];  const float* b2 = (const float*)d_in[8];
    const float* g2 = (const float*)d_in[9];  const float* be2= (const float*)d_in[10];
    const float* w3 = (const float*)d_in[11]; const float* b3 = (const float*)d_in[12];
    const float* g3 = (const float*)d_in[13]; const float* be3= (const float*)d_in[14];
    const float* w4 = (const float*)d_in[15]; const float* b4 = (const float*)d_in[16];
    float* out = (float*)d_out;

    char* ws = (char*)d_ws;
    unsigned* mm  = (unsigned*)(ws + O_MM);
    float* st1    = (float*)(ws + O_ST1);
    float* st2    = (float*)(ws + O_ST2);
    float* st3    = (float*)(ws + O_ST3);
    unsigned* STb = (unsigned*)(ws + O_STB);
    float* h      = (float*)(ws + O_H);
    float* A1     = (float*)(ws + O_A1);
    float* A2     = (float*)(ws + O_A2);
    float* A3     = (float*)(ws + O_A3);

    hipMemsetAsync(ws + O_MM, 0xFF, 1024, stream);            // min init
    hipMemsetAsync(ws + O_MM + 1024, 0x00, 1024, stream);     // max init
    hipMemsetAsync(ws + O_ST1, 0x00, 3584, stream);           // stats zero

    k_prep<<<384, 256, 0, stream>>>(x, fs, grids, mm, STb);
    k_gather<<<2048, 128, 0, stream>>>(x, mm, STb, h);
    k_gemm<0><<<dim3(4, 64), 256, 0, stream>>>(h,  w1, b1, nullptr, nullptr, nullptr, A1, st1, 128, 256);
    k_gemm<1><<<dim3(2, 64), 256, 0, stream>>>(A1, w2, b2, st1, g1, be1,            A2, st2, 256, 128);
    k_gemm<1><<<dim3(1, 64), 256, 0, stream>>>(A2, w3, b3, st2, g2, be2,            A3, st3, 128, 64);
    k_final<<<16, 256, 0, stream>>>(A3, st3, g3, be3, w4, b4, out);
}